// Round 16
// baseline (329.393 us; speedup 1.0000x reference)
//
#include <hip/hip_runtime.h>

#define GN_EPS 1e-5f

constexpr int NB   = 64;             // graphs
constexpr int EPG  = 16384;          // edges per graph (static)
constexpr int ETOT = NB * EPG;       // 1048576 edges
constexpr int NTOT = 64 * 1024;      // original nodes

// ---------------------------------------------------------------- cmap init (identity)
__global__ void cmap_init_kernel(int* __restrict__ cmap) {
    int i = blockIdx.x * blockDim.x + threadIdx.x;
    if (i < NTOT) cmap[i] = i;
}

// ---------------------------------------------------------------- fused per-graph CSR build
// One 1024-thread block per graph. Optionally composes cmap with the previous
// layer's mapping first (graph-local). Emits PACKED edge records (src, dinv[src]).
template <int NPG>   // nodes per graph this layer: 1024 / 512 / 256
__global__ __launch_bounds__(1024) void csr_build_kernel(
        const int* __restrict__ ei, int* __restrict__ cmap,
        const int* __restrict__ mapping, int do_compose,
        int* __restrict__ cnt, int* __restrict__ offs, float* __restrict__ dinv,
        int2* __restrict__ csr_pack) {
    __shared__ int   lcnt[NPG];
    __shared__ float sdv[NPG];
    __shared__ int   wsum[16];
    constexpr int NW = NPG / 64;
    const int g = blockIdx.x;
    const int t = threadIdx.x;           // 1024 threads
    const int ebase = g * EPG;
    constexpr int EPT = EPG / 1024;      // 16

    if (do_compose) {
        int i = g * 1024 + t;            // orig nodes per graph = 1024
        int c = cmap[i];
        cmap[i] = (c >= 0) ? mapping[c] : -1;
    }
    for (int i = t; i < NPG; i += 1024) lcnt[i] = 0;
    __syncthreads();

    int ms_[EPT], md_[EPT];
#pragma unroll
    for (int i = 0; i < EPT; i++) {
        int e = ebase + t + i * 1024;                // coalesced
        int s = cmap[ei[e]];
        int d = cmap[ei[ETOT + e]];
        bool ok = (s >= 0) && (d >= 0);
        ms_[i] = ok ? s : -1;
        md_[i] = ok ? (d - g * NPG) : 0;
        if (ok) atomicAdd(&lcnt[d - g * NPG], 1);
    }
    __syncthreads();

    // ---- exclusive scan via wave shfl
    const int lane = t & 63;
    const int wid  = t >> 6;
    int orig = (t < NPG) ? lcnt[t] : 0;
    int v = orig;
#pragma unroll
    for (int d = 1; d < 64; d <<= 1) {
        int u = __shfl_up(v, d);
        if (lane >= d) v += u;
    }
    if (lane == 63) wsum[wid] = v;
    __syncthreads();
    if (wid == 0) {
        int wv = (lane < NW) ? wsum[lane] : 0;
#pragma unroll
        for (int d = 1; d < 16; d <<= 1) {
            int u = __shfl_up(wv, d);
            if (lane >= d) wv += u;
        }
        if (lane < NW) wsum[lane] = wv;
    }
    __syncthreads();
    if (t < NPG) {
        int incl = v + ((wid > 0) ? wsum[wid - 1] : 0);
        int excl = incl - orig;
        float dv = rsqrtf(1.0f + (float)orig);
        cnt[g * NPG + t]  = orig;
        offs[g * NPG + t] = ebase + excl;
        dinv[g * NPG + t] = dv;
        sdv[t] = dv;
        lcnt[t] = excl;                              // fill cursor
    }
    __syncthreads();

#pragma unroll
    for (int i = 0; i < EPT; i++) {
        int s = ms_[i];
        if (s >= 0) {
            int pos = atomicAdd(&lcnt[md_[i]], 1);
            csr_pack[ebase + pos] = make_int2(s, __float_as_int(sdv[s - g * NPG]));
        }
    }
}

// ---------------------------------------------------------------- weighted CSR gather (PRE-GEMM, packed, 2-deep)
// z[v] = dinv[v] * ( dinv[v]*x[v] + sum_src dinv[src]*x[src] )
template <int D4>   // float4s per row: 25 (din=100) or 32 (din=128)
__global__ __launch_bounds__(256) void gather_kernel(
        const float* __restrict__ x, const int* __restrict__ cnt,
        const int* __restrict__ offs, const float* __restrict__ dinv,
        const int2* __restrict__ csr_pack, float* __restrict__ z, int n, int bpg) {
    constexpr int GRP = 8;
    constexpr int NPB = 256 / GRP;       // 32 nodes per block
    constexpr int CPL = 4;               // float4s per lane
    int bid   = blockIdx.x;
    int xcd   = bid & 7;
    int slot  = bid >> 3;
    int graph = xcd + 8 * (slot / bpg);
    int local = slot % bpg;
    int vb    = graph * bpg + local;

    int grp  = threadIdx.x / GRP;
    int lane = threadIdx.x % GRP;
    int v = vb * NPB + grp;
    if (v >= n) return;

    const float4* x4 = reinterpret_cast<const float4*>(x);
    int st = offs[v];
    int c  = cnt[v];
    float dv = dinv[v];

    int f4_[CPL];
    bool act[CPL];
#pragma unroll
    for (int i = 0; i < CPL; i++) {
        f4_[i] = lane + GRP * i;
        act[i] = f4_[i] < D4;
    }

    float4 acc[CPL];
#pragma unroll
    for (int i = 0; i < CPL; i++) {
        if (act[i]) {
            float4 xv = x4[(size_t)v * D4 + f4_[i]];
            acc[i] = {xv.x * dv, xv.y * dv, xv.z * dv, xv.w * dv};
        } else {
            acc[i] = {0.f, 0.f, 0.f, 0.f};
        }
    }

    int j = 0;
    for (; j + 2 <= c; j += 2) {
        int2 p0 = csr_pack[st + j];
        int2 p1 = csr_pack[st + j + 1];
        float d0 = __int_as_float(p0.y);
        float d1 = __int_as_float(p1.y);
        size_t r0 = (size_t)p0.x * D4;
        size_t r1 = (size_t)p1.x * D4;
#pragma unroll
        for (int i = 0; i < CPL; i++) {
            if (!act[i]) continue;
            float4 h0 = x4[r0 + f4_[i]];
            float4 h1 = x4[r1 + f4_[i]];
            acc[i].x += h0.x * d0 + h1.x * d1;
            acc[i].y += h0.y * d0 + h1.y * d1;
            acc[i].z += h0.z * d0 + h1.z * d1;
            acc[i].w += h0.w * d0 + h1.w * d1;
        }
    }
    if (j < c) {
        int2 p0 = csr_pack[st + j];
        float d0 = __int_as_float(p0.y);
        size_t r0 = (size_t)p0.x * D4;
#pragma unroll
        for (int i = 0; i < CPL; i++) {
            if (!act[i]) continue;
            float4 h0 = x4[r0 + f4_[i]];
            acc[i].x += h0.x * d0; acc[i].y += h0.y * d0;
            acc[i].z += h0.z * d0; acc[i].w += h0.w * d0;
        }
    }
#pragma unroll
    for (int i = 0; i < CPL; i++) {
        if (!act[i]) continue;
        float4 o = {acc[i].x * dv, acc[i].y * dv, acc[i].z * dv, acc[i].w * dv};
        reinterpret_cast<float4*>(z)[(size_t)v * D4 + f4_[i]] = o;
    }
}

// ---------------------------------------------------------------- GEMM  C = A@W + b, epilogue emits gn partial sums
__global__ __launch_bounds__(256) void gemm128_kernel(const float* __restrict__ A,
                                                      const float* __restrict__ W,
                                                      const float* __restrict__ Bias,
                                                      float* __restrict__ C,
                                                      float* __restrict__ sum1,
                                                      float* __restrict__ sum2,
                                                      int M, int N, int K, int nper) {
    __shared__ float As[16][132];
    __shared__ float Bs[16][132];
    __shared__ float red1[4][132];
    __shared__ float red2[4][132];
    const int bm = blockIdx.x * 128;
    const int bn = blockIdx.y * 128;
    const int tid = threadIdx.x;
    const int tx = tid & 15, ty = tid >> 4;

    const int arow = tid >> 1;          // 0..127
    const int ak   = (tid & 1) * 8;     // 0 or 8
    const int brow = tid >> 5;          // 0..7
    const int bc4  = (tid & 31) * 4;    // 0..124

    float acc[2][2][4][4] = {};

    for (int k0 = 0; k0 < K; k0 += 16) {
        {   // stage A (transpose to [k][m])
            const float* ap = A + (size_t)(bm + arow) * K + k0 + ak;
            float4 a0 = {0,0,0,0}, a1 = {0,0,0,0};
            if (k0 + ak < K)     a0 = *reinterpret_cast<const float4*>(ap);
            if (k0 + ak + 4 < K) a1 = *reinterpret_cast<const float4*>(ap + 4);
            As[ak + 0][arow] = a0.x; As[ak + 1][arow] = a0.y;
            As[ak + 2][arow] = a0.z; As[ak + 3][arow] = a0.w;
            As[ak + 4][arow] = a1.x; As[ak + 5][arow] = a1.y;
            As[ak + 6][arow] = a1.z; As[ak + 7][arow] = a1.w;
        }
        {   // stage B
            float4 b0 = {0,0,0,0}, b1 = {0,0,0,0};
            if (k0 + brow < K)
                b0 = *reinterpret_cast<const float4*>(W + (size_t)(k0 + brow) * N + bn + bc4);
            if (k0 + brow + 8 < K)
                b1 = *reinterpret_cast<const float4*>(W + (size_t)(k0 + brow + 8) * N + bn + bc4);
            *reinterpret_cast<float4*>(&Bs[brow][bc4])     = b0;
            *reinterpret_cast<float4*>(&Bs[brow + 8][bc4]) = b1;
        }
        __syncthreads();
#pragma unroll
        for (int k = 0; k < 16; k++) {
            float4 a0 = *reinterpret_cast<const float4*>(&As[k][ty * 4]);
            float4 a1 = *reinterpret_cast<const float4*>(&As[k][64 + ty * 4]);
            float4 b0 = *reinterpret_cast<const float4*>(&Bs[k][tx * 4]);
            float4 b1 = *reinterpret_cast<const float4*>(&Bs[k][64 + tx * 4]);
            const float av[2][4] = {{a0.x, a0.y, a0.z, a0.w}, {a1.x, a1.y, a1.z, a1.w}};
            const float bv[2][4] = {{b0.x, b0.y, b0.z, b0.w}, {b1.x, b1.y, b1.z, b1.w}};
#pragma unroll
            for (int qi = 0; qi < 2; qi++)
#pragma unroll
                for (int qj = 0; qj < 2; qj++)
#pragma unroll
                    for (int i = 0; i < 4; i++)
#pragma unroll
                        for (int j = 0; j < 4; j++)
                            acc[qi][qj][i][j] += av[qi][i] * bv[qj][j];
        }
        __syncthreads();
    }
    float4 bb[2];
    bb[0] = *reinterpret_cast<const float4*>(&Bias[bn + tx * 4]);
    bb[1] = *reinterpret_cast<const float4*>(&Bias[bn + 64 + tx * 4]);

    float s1l[2][4] = {}, s2l[2][4] = {};
#pragma unroll
    for (int qi = 0; qi < 2; qi++)
#pragma unroll
        for (int i = 0; i < 4; i++) {
            int row = bm + qi * 64 + ty * 4 + i;
#pragma unroll
            for (int qj = 0; qj < 2; qj++) {
                float o0 = acc[qi][qj][i][0] + bb[qj].x;
                float o1 = acc[qi][qj][i][1] + bb[qj].y;
                float o2 = acc[qi][qj][i][2] + bb[qj].z;
                float o3 = acc[qi][qj][i][3] + bb[qj].w;
                float4 o = {o0, o1, o2, o3};
                *reinterpret_cast<float4*>(&C[(size_t)row * N + bn + qj * 64 + tx * 4]) = o;
                s1l[qj][0] += o0; s2l[qj][0] += o0 * o0;
                s1l[qj][1] += o1; s2l[qj][1] += o1 * o1;
                s1l[qj][2] += o2; s2l[qj][2] += o2 * o2;
                s1l[qj][3] += o3; s2l[qj][3] += o3 * o3;
            }
        }
    const int wv = tid >> 6;
#pragma unroll
    for (int qj = 0; qj < 2; qj++)
#pragma unroll
        for (int j = 0; j < 4; j++) {
            float v1 = s1l[qj][j], v2 = s2l[qj][j];
            v1 += __shfl_xor(v1, 16); v1 += __shfl_xor(v1, 32);
            v2 += __shfl_xor(v2, 16); v2 += __shfl_xor(v2, 32);
            if ((tid & 48) == 0) {
                red1[wv][tx * 8 + qj * 4 + j] = v1;
                red2[wv][tx * 8 + qj * 4 + j] = v2;
            }
        }
    __syncthreads();
    if (tid < 16) {
        const int g   = bm / nper;
        const int nch = nper >> 7;
        const int ch  = (bm % nper) >> 7;
        size_t slotbase = (size_t)(g * nch + ch) * N + bn;
#pragma unroll
        for (int qj = 0; qj < 2; qj++)
#pragma unroll
            for (int j = 0; j < 4; j++) {
                int k = tid * 8 + qj * 4 + j;
                float v1 = red1[0][k] + red1[1][k] + red1[2][k] + red1[3][k];
                float v2 = red2[0][k] + red2[1][k] + red2[2][k] + red2[3][k];
                sum1[slotbase + qj * 64 + tid * 4 + j] = v1;
                sum2[slotbase + qj * 64 + tid * 4 + j] = v2;
            }
    }
}

// ---------------------------------------------------------------- 1/||p|| for all 3 layers in one launch
__global__ void pnorm3_kernel(const float* __restrict__ p0, const float* __restrict__ p1,
                              const float* __restrict__ p2, int d0, int d1, int d2,
                              float* __restrict__ out) {
    __shared__ float red[256];
    const float* p = (blockIdx.x == 0) ? p0 : (blockIdx.x == 1) ? p1 : p2;
    int d          = (blockIdx.x == 0) ? d0 : (blockIdx.x == 1) ? d1 : d2;
    int t = threadIdx.x;
    float v = (t < d) ? p[t] : 0.0f;
    red[t] = v * v;
    __syncthreads();
    for (int s = 128; s; s >>= 1) {
        if (t < s) red[t] += red[t + s];
        __syncthreads();
    }
    if (t == 0) out[blockIdx.x] = 1.0f / sqrtf(red[0]);
}

// ---------------------------------------------------------------- gn stats helper (device)
template <int DO>
__device__ __forceinline__ void gn_stats_to_lds(
        const float* __restrict__ sum1, const float* __restrict__ sum2,
        const float* __restrict__ ms, const float* __restrict__ w,
        float* scm, float* ssr, int g, int n_per, int nch, int tid, int nthr) {
    float inv_n = 1.0f / (float)n_per;
    for (int f = tid; f < DO; f += nthr) {
        float s1 = 0.f, s2 = 0.f;
        for (int ch = 0; ch < nch; ch++) {
            s1 += sum1[(size_t)(g * nch + ch) * DO + f];
            s2 += sum2[(size_t)(g * nch + ch) * DO + f];
        }
        float mean = s1 * inv_n;
        float ex2  = s2 * inv_n;
        float m = ms[f];
        float var = ex2 - 2.f * m * mean * mean + m * m * mean * mean;
        scm[f] = m * mean;
        ssr[f] = w[f] * rsqrtf(var + GN_EPS);
    }
}

// ---------------------------------------------------------------- score-only: normalize in regs, dot, tanh
template <int DO>
__global__ __launch_bounds__(256) void gn_score_kernel(
        const float* __restrict__ x, const float* __restrict__ sum1,
        const float* __restrict__ sum2, const float* __restrict__ ms,
        const float* __restrict__ w, const float* __restrict__ bias,
        const float* __restrict__ p, const float* __restrict__ pinv,
        float* __restrict__ score, int n_per, int nch) {
    constexpr int V = DO / 64;
    __shared__ float scm[DO];
    __shared__ float ssr[DO];
    int node = blockIdx.x * 4 + (threadIdx.x >> 6);
    int lane = threadIdx.x & 63;
    int g = node / n_per;
    gn_stats_to_lds<DO>(sum1, sum2, ms, w, scm, ssr, g, n_per, nch, threadIdx.x, 256);
    __syncthreads();

    const float* xr = x + (size_t)node * DO + lane * V;
    const float* bb = bias + lane * V;
    const float* pp = p + lane * V;
    float dot = 0.f;
#pragma unroll
    for (int i = 0; i < V; i++) {
        int f = lane * V + i;
        float y = (xr[i] - scm[f]) * ssr[f] + bb[i];
        y = fmaxf(y, 0.0f);
        dot += y * pp[i];
    }
#pragma unroll
    for (int off = 32; off; off >>= 1) dot += __shfl_xor(dot, off);
    if (lane == 0) score[node] = tanhf(dot * pinv[0]);
}

// ---------------------------------------------------------------- top-k via radix select (shfl final scan)
template <int N, int K>
__global__ __launch_bounds__(1024) void topk_radix_kernel(
        const float* __restrict__ score, int* __restrict__ mapping,
        int* __restrict__ inv) {
    __shared__ int hist[256];
    __shared__ int sscan[256];
    __shared__ int wsum[16];
    __shared__ int sbyte, sneed;
    constexpr int NW = N / 64;
    const int g = blockIdx.x;
    const int t = threadIdx.x;       // blockDim == N
    float sc = score[g * N + t];
    unsigned u = __float_as_uint(sc);
    unsigned key = (u & 0x80000000u) ? ~u : (u | 0x80000000u);   // monotone

    unsigned prefix = 0;
    int need = K;
#pragma unroll
    for (int shift = 24; shift >= 0; shift -= 8) {
        if (t < 256) hist[t] = 0;
        __syncthreads();
        unsigned hm = (shift == 24) ? 0u : (0xFFFFFFFFu << (shift + 8));
        if ((key & hm) == (prefix & hm))
            atomicAdd(&hist[(key >> shift) & 255], 1);
        __syncthreads();
        if (t < 256) sscan[t] = hist[t];
        __syncthreads();
        for (int d = 1; d < 256; d <<= 1) {
            int x = (t < 256 && t + d < 256) ? sscan[t + d] : 0;
            __syncthreads();
            if (t < 256) sscan[t] += x;
            __syncthreads();
        }
        if (t < 256) {
            int ge  = sscan[t];
            int gt_ = (t + 1 < 256) ? sscan[t + 1] : 0;
            if (ge >= need && gt_ < need) { sbyte = t; sneed = need - gt_; }
        }
        __syncthreads();
        prefix |= ((unsigned)sbyte << shift);
        need = sneed;
        __syncthreads();
    }
    // packed (gt|eq) exclusive scan via wave shfl
    bool gt = key > prefix;
    bool eq = (key == prefix);
    int val = (gt ? (1 << 16) : 0) | (eq ? 1 : 0);
    const int lane = t & 63;
    const int wid  = t >> 6;
    int v = val;
#pragma unroll
    for (int d = 1; d < 64; d <<= 1) {
        int u2 = __shfl_up(v, d);
        if (lane >= d) v += u2;
    }
    if (lane == 63) wsum[wid] = v;
    __syncthreads();
    if (wid == 0) {
        int wv = (lane < NW) ? wsum[lane] : 0;
#pragma unroll
        for (int d = 1; d < 16; d <<= 1) {
            int u2 = __shfl_up(wv, d);
            if (lane >= d) wv += u2;
        }
        if (lane < NW) wsum[lane] = wv;
    }
    __syncthreads();
    int incl = v + ((wid > 0) ? wsum[wid - 1] : 0);
    int gtrank = (incl >> 16) - (gt ? 1 : 0);
    int eqrank = (incl & 0xFFFF) - (eq ? 1 : 0);
    int cntGT  = K - need;
    bool sel = gt || (eq && (eqrank < need));
    int old_g = g * N + t;
    if (sel) {
        int slot = gt ? gtrank : (cntGT + eqrank);
        mapping[old_g] = g * K + slot;
        inv[g * K + slot] = old_g;
    } else {
        mapping[old_g] = -1;
    }
}

// ---------------------------------------------------------------- permute + normalize + relu + scale (fused)
// X2[new] = relu((X1[old]-scm)*ssr + bias) * score[old]
template <int DO>
__global__ __launch_bounds__(256) void permute_norm_kernel(
        const float* __restrict__ x, const int* __restrict__ inv,
        const float* __restrict__ score, const float* __restrict__ sum1,
        const float* __restrict__ sum2, const float* __restrict__ ms,
        const float* __restrict__ w, const float* __restrict__ bias,
        float* __restrict__ xn, int n_per, int nch, int kk) {
    constexpr int V = DO / 64;
    __shared__ float scm[DO];
    __shared__ float ssr[DO];
    int node = blockIdx.x * 4 + (threadIdx.x >> 6);    // new index
    int lane = threadIdx.x & 63;
    int g = node / kk;
    gn_stats_to_lds<DO>(sum1, sum2, ms, w, scm, ssr, g, n_per, nch, threadIdx.x, 256);
    __syncthreads();

    int old = inv[node];
    float sc = score[old];
    const float* xr = x + (size_t)old * DO + lane * V;
    const float* bb = bias + lane * V;
    float* xo = xn + (size_t)node * DO + lane * V;
#pragma unroll
    for (int i = 0; i < V; i++) {
        int f = lane * V + i;
        float y = (xr[i] - scm[f]) * ssr[f] + bb[i];
        y = fmaxf(y, 0.0f);
        xo[i] = y * sc;
    }
}

// ---------------------------------------------------------------- final select + normalize + pool (fused)
__global__ __launch_bounds__(1024) void pool_sel_kernel(
        const float* __restrict__ x, const int* __restrict__ inv,
        const float* __restrict__ score, const float* __restrict__ sum1,
        const float* __restrict__ sum2, const float* __restrict__ ms,
        const float* __restrict__ w, const float* __restrict__ bias,
        float* __restrict__ out, int n_per, int nch) {
    __shared__ float scm[256];
    __shared__ float ssr[256];
    __shared__ float ssum[1024];
    __shared__ float smax[1024];
    int g = blockIdx.x;
    int f = threadIdx.x & 255;
    int ch = threadIdx.x >> 8;       // 0..3
    gn_stats_to_lds<256>(sum1, sum2, ms, w, scm, ssr, g, n_per, nch, threadIdx.x, 1024);
    __syncthreads();
    float cm = scm[f], sr = ssr[f], bb = bias[f];
    float s = 0.f, mx = -INFINITY;
    for (int i = ch; i < 128; i += 4) {
        int old = inv[g * 128 + i];
        float sc = score[old];
        float y = (x[(size_t)old * 256 + f] - cm) * sr + bb;
        y = fmaxf(y, 0.0f) * sc;
        s += y;
        mx = fmaxf(mx, y);
    }
    ssum[threadIdx.x] = s;
    smax[threadIdx.x] = mx;
    __syncthreads();
    if (ch == 0) {
#pragma unroll
        for (int c = 1; c < 4; c++) {
            s  += ssum[f + c * 256];
            mx  = fmaxf(mx, smax[f + c * 256]);
        }
        out[g * 512 + f]       = s / 128.0f;
        out[g * 512 + 256 + f] = mx;
    }
}

// ================================================================ host
static inline int cdiv_h(int a, int b) { return (a + b - 1) / b; }

extern "C" void kernel_launch(void* const* d_in, const int* in_sizes, int n_in,
                              void* d_out, int out_size, void* d_ws, size_t ws_size,
                              hipStream_t stream) {
    (void)in_sizes; (void)n_in; (void)out_size; (void)ws_size;

    const float* x_in = (const float*)d_in[0];
    const int*   ei   = (const int*)d_in[1];
    // d_in[2] = batch (unused, equal-sized graphs)
    const float* Wm[3]  = {(const float*)d_in[3],  (const float*)d_in[9],  (const float*)d_in[15]};
    const float* bv[3]  = {(const float*)d_in[4],  (const float*)d_in[10], (const float*)d_in[16]};
    const float* gnw[3] = {(const float*)d_in[5],  (const float*)d_in[11], (const float*)d_in[17]};
    const float* gnb[3] = {(const float*)d_in[6],  (const float*)d_in[12], (const float*)d_in[18]};
    const float* gnm[3] = {(const float*)d_in[7],  (const float*)d_in[13], (const float*)d_in[19]};
    const float* pv[3]  = {(const float*)d_in[8],  (const float*)d_in[14], (const float*)d_in[20]};

    // workspace carve
    size_t off = 0;
    auto alloc = [&](size_t bytes) {
        void* p = (char*)d_ws + off;
        off += (bytes + 255) & ~(size_t)255;
        return p;
    };
    float* X1      = (float*)alloc((size_t)65536 * 128 * 4);   // gemm out (L2: 16384x256)
    float* Z       = (float*)alloc((size_t)65536 * 128 * 4);   // gather out (pre-gemm)
    float* X2      = (float*)alloc((size_t)32768 * 128 * 4);   // permuted x for next layer
    int2*  csr_pack= (int2*)alloc((size_t)ETOT * 8);
    int*   cmap    = (int*)alloc(NTOT * 4);
    int*   cnt     = (int*)alloc(65536 * 4);
    int*   offs    = (int*)alloc(65536 * 4);
    float* dinv    = (float*)alloc(65536 * 4);
    float* score   = (float*)alloc(65536 * 4);
    int*   mapping = (int*)alloc(65536 * 4);
    int*   inv     = (int*)alloc(32768 * 4);
    float* sum1    = (float*)alloc(64 * 8 * 256 * 4);   // per-chunk slots
    float* sum2    = (float*)alloc(64 * 8 * 256 * 4);
    float* pinv    = (float*)alloc(256);

    const int nper[4] = {1024, 512, 256, 128};
    const int din[3]  = {100, 128, 128};
    const int dof[3]  = {128, 128, 256};

    cmap_init_kernel<<<NTOT / 256, 256, 0, stream>>>(cmap);
    pnorm3_kernel<<<3, 256, 0, stream>>>(pv[0], pv[1], pv[2], dof[0], dof[1], dof[2], pinv);

    for (int L = 0; L < 3; L++) {
        const int n    = NB * nper[L];
        const int k    = nper[L + 1];
        const int nn   = NB * k;
        const int D    = dof[L];
        const int nch  = nper[L] / 128;
        const float* xin = (L == 0) ? x_in : X2;

        // ---- fused CSR build (+ inline cmap composition for L>0)
        if (nper[L] == 1024)
            csr_build_kernel<1024><<<NB, 1024, 0, stream>>>(ei, cmap, mapping, 0,
                                                            cnt, offs, dinv, csr_pack);
        else if (nper[L] == 512)
            csr_build_kernel<512><<<NB, 1024, 0, stream>>>(ei, cmap, mapping, 1,
                                                           cnt, offs, dinv, csr_pack);
        else
            csr_build_kernel<256><<<NB, 1024, 0, stream>>>(ei, cmap, mapping, 1,
                                                           cnt, offs, dinv, csr_pack);

        // ---- weighted aggregate on raw x (din-wide)
        {
            const int NPB = 32;
            const int bpg = nper[L] / NPB;
            if (L == 0)
                gather_kernel<25><<<n / NPB, 256, 0, stream>>>(xin, cnt, offs, dinv,
                                                               csr_pack, Z, n, bpg);
            else
                gather_kernel<32><<<n / NPB, 256, 0, stream>>>(xin, cnt, offs, dinv,
                                                               csr_pack, Z, n, bpg);
        }

        // ---- X1 = Z @ W + b   (epilogue writes graphnorm partial sums)
        gemm128_kernel<<<dim3(n / 128, D / 128), 256, 0, stream>>>(Z, Wm[L], bv[L], X1,
                                                                   sum1, sum2,
                                                                   n, D, din[L], nper[L]);

        // ---- score only (normalize in registers; no X1 writeback)
        if (D == 128)
            gn_score_kernel<128><<<n / 4, 256, 0, stream>>>(X1, sum1, sum2, gnm[L], gnw[L],
                                                            gnb[L], pv[L], pinv + L,
                                                            score, nper[L], nch);
        else
            gn_score_kernel<256><<<n / 4, 256, 0, stream>>>(X1, sum1, sum2, gnm[L], gnw[L],
                                                            gnb[L], pv[L], pinv + L,
                                                            score, nper[L], nch);

        // ---- top-k pooling (radix select)
        if (nper[L] == 1024)
            topk_radix_kernel<1024, 512><<<NB, 1024, 0, stream>>>(score, mapping, inv);
        else if (nper[L] == 512)
            topk_radix_kernel<512, 256><<<NB, 512, 0, stream>>>(score, mapping, inv);
        else
            topk_radix_kernel<256, 128><<<NB, 256, 0, stream>>>(score, mapping, inv);

        if (L < 2) {
            // normalize+relu+scale applied only to the selected half, into X2
            if (D == 128)
                permute_norm_kernel<128><<<nn / 4, 256, 0, stream>>>(
                    X1, inv, score, sum1, sum2, gnm[L], gnw[L], gnb[L], X2,
                    nper[L], nch, k);
            else
                permute_norm_kernel<256><<<nn / 4, 256, 0, stream>>>(
                    X1, inv, score, sum1, sum2, gnm[L], gnw[L], gnb[L], X2,
                    nper[L], nch, k);
        } else {
            pool_sel_kernel<<<NB, 1024, 0, stream>>>(X1, inv, score, sum1, sum2,
                                                     gnm[L], gnw[L], gnb[L],
                                                     (float*)d_out, nper[L], nch);
        }
    }
}

// Round 17
// 309.666 us; speedup vs baseline: 1.0637x; 1.0637x over previous
//
#include <hip/hip_runtime.h>

#define GN_EPS 1e-5f

constexpr int NB   = 64;             // graphs
constexpr int EPG  = 16384;          // edges per graph (static)
constexpr int ETOT = NB * EPG;       // 1048576 edges
constexpr int NTOT = 64 * 1024;      // original nodes

// ---------------------------------------------------------------- cmap init (identity)
__global__ void cmap_init_kernel(int* __restrict__ cmap) {
    int i = blockIdx.x * blockDim.x + threadIdx.x;
    if (i < NTOT) cmap[i] = i;
}

// ---------------------------------------------------------------- compose mapping: cmap = mapping o cmap
__global__ void compose_map_kernel(int* __restrict__ cmap, const int* __restrict__ mapping) {
    int i = blockIdx.x * blockDim.x + threadIdx.x;
    if (i >= NTOT) return;
    int c = cmap[i];
    cmap[i] = (c >= 0) ? mapping[c] : -1;
}

// ---------------------------------------------------------------- fused per-graph CSR build
template <int NPG>   // nodes per graph this layer: 1024 / 512 / 256
__global__ __launch_bounds__(1024) void csr_build_kernel(
        const int* __restrict__ ei, const int* __restrict__ cmap,
        int* __restrict__ cnt, int* __restrict__ offs, float* __restrict__ dinv,
        int* __restrict__ csr_src) {
    __shared__ int lcnt[NPG];
    __shared__ int lscan[NPG];
    const int g = blockIdx.x;
    const int t = threadIdx.x;           // 1024 threads
    const int ebase = g * EPG;
    constexpr int EPT = EPG / 1024;      // 16

    for (int i = t; i < NPG; i += 1024) lcnt[i] = 0;
    __syncthreads();

    int ms_[EPT], md_[EPT];
#pragma unroll
    for (int i = 0; i < EPT; i++) {
        int e = ebase + t + i * 1024;                // coalesced
        int s = cmap[ei[e]];
        int d = cmap[ei[ETOT + e]];
        bool ok = (s >= 0) && (d >= 0);
        ms_[i] = ok ? s : -1;
        md_[i] = ok ? (d - g * NPG) : 0;
        if (ok) atomicAdd(&lcnt[d - g * NPG], 1);
    }
    __syncthreads();

    // exclusive scan over NPG entries (first NPG threads)
    if (t < NPG) lscan[t] = lcnt[t];
    __syncthreads();
    for (int d = 1; d < NPG; d <<= 1) {
        int x = 0;
        if (t < NPG && t >= d) x = lscan[t - d];
        __syncthreads();
        if (t < NPG) lscan[t] += x;
        __syncthreads();
    }
    if (t < NPG) {
        int v = lcnt[t];
        int excl = lscan[t] - v;
        cnt[g * NPG + t]  = v;
        offs[g * NPG + t] = ebase + excl;
        dinv[g * NPG + t] = rsqrtf(1.0f + (float)v);
        lcnt[t] = excl;                              // fill cursor
    }
    __syncthreads();

#pragma unroll
    for (int i = 0; i < EPT; i++) {
        if (ms_[i] >= 0) {
            int pos = atomicAdd(&lcnt[md_[i]], 1);
            csr_src[ebase + pos] = ms_[i];
        }
    }
}

// ---------------------------------------------------------------- GEMM  Hs[M,N] = (A[M,K] @ W[K,N]) * dinv[row]
__global__ __launch_bounds__(256) void gemm128_kernel(const float* __restrict__ A,
                                                      const float* __restrict__ W,
                                                      const float* __restrict__ dinv,
                                                      float* __restrict__ C,
                                                      int M, int N, int K) {
    __shared__ float As[16][132];
    __shared__ float Bs[16][132];
    const int bm = blockIdx.x * 128;
    const int bn = blockIdx.y * 128;
    const int tid = threadIdx.x;
    const int tx = tid & 15, ty = tid >> 4;

    const int arow = tid >> 1;          // 0..127
    const int ak   = (tid & 1) * 8;     // 0 or 8
    const int brow = tid >> 5;          // 0..7
    const int bc4  = (tid & 31) * 4;    // 0..124

    float acc[2][2][4][4] = {};

    for (int k0 = 0; k0 < K; k0 += 16) {
        {   // stage A (transpose to [k][m])
            const float* ap = A + (size_t)(bm + arow) * K + k0 + ak;
            float4 a0 = {0,0,0,0}, a1 = {0,0,0,0};
            if (k0 + ak < K)     a0 = *reinterpret_cast<const float4*>(ap);
            if (k0 + ak + 4 < K) a1 = *reinterpret_cast<const float4*>(ap + 4);
            As[ak + 0][arow] = a0.x; As[ak + 1][arow] = a0.y;
            As[ak + 2][arow] = a0.z; As[ak + 3][arow] = a0.w;
            As[ak + 4][arow] = a1.x; As[ak + 5][arow] = a1.y;
            As[ak + 6][arow] = a1.z; As[ak + 7][arow] = a1.w;
        }
        {   // stage B
            float4 b0 = {0,0,0,0}, b1 = {0,0,0,0};
            if (k0 + brow < K)
                b0 = *reinterpret_cast<const float4*>(W + (size_t)(k0 + brow) * N + bn + bc4);
            if (k0 + brow + 8 < K)
                b1 = *reinterpret_cast<const float4*>(W + (size_t)(k0 + brow + 8) * N + bn + bc4);
            *reinterpret_cast<float4*>(&Bs[brow][bc4])     = b0;
            *reinterpret_cast<float4*>(&Bs[brow + 8][bc4]) = b1;
        }
        __syncthreads();
#pragma unroll
        for (int k = 0; k < 16; k++) {
            float4 a0 = *reinterpret_cast<const float4*>(&As[k][ty * 4]);
            float4 a1 = *reinterpret_cast<const float4*>(&As[k][64 + ty * 4]);
            float4 b0 = *reinterpret_cast<const float4*>(&Bs[k][tx * 4]);
            float4 b1 = *reinterpret_cast<const float4*>(&Bs[k][64 + tx * 4]);
            const float av[2][4] = {{a0.x, a0.y, a0.z, a0.w}, {a1.x, a1.y, a1.z, a1.w}};
            const float bv[2][4] = {{b0.x, b0.y, b0.z, b0.w}, {b1.x, b1.y, b1.z, b1.w}};
#pragma unroll
            for (int qi = 0; qi < 2; qi++)
#pragma unroll
                for (int qj = 0; qj < 2; qj++)
#pragma unroll
                    for (int i = 0; i < 4; i++)
#pragma unroll
                        for (int j = 0; j < 4; j++)
                            acc[qi][qj][i][j] += av[qi][i] * bv[qj][j];
        }
        __syncthreads();
    }
#pragma unroll
    for (int qi = 0; qi < 2; qi++)
#pragma unroll
        for (int i = 0; i < 4; i++) {
            int row = bm + qi * 64 + ty * 4 + i;
            float dv = dinv[row];
#pragma unroll
            for (int qj = 0; qj < 2; qj++) {
                float4 o = {acc[qi][qj][i][0] * dv, acc[qi][qj][i][1] * dv,
                            acc[qi][qj][i][2] * dv, acc[qi][qj][i][3] * dv};
                *reinterpret_cast<float4*>(&C[(size_t)row * N + bn + qj * 64 + tx * 4]) = o;
            }
        }
}

// ---------------------------------------------------------------- CSR gather
// out = dinv[v] * (Hs[v] + sum Hs[src]) + b     (Hs already row-scaled)
template <int D4>   // 32 (D=128) or 64 (D=256)
__global__ __launch_bounds__(256) void gather_kernel(
        const float* __restrict__ hs, const int* __restrict__ cnt,
        const int* __restrict__ offs, const float* __restrict__ dinv,
        const int* __restrict__ csr_src, const float* __restrict__ b,
        float* __restrict__ out, int n, int bpg) {
    constexpr int NPB = 256 / D4;
    int bid   = blockIdx.x;
    int xcd   = bid & 7;
    int slot  = bid >> 3;
    int graph = xcd + 8 * (slot / bpg);
    int local = slot % bpg;
    int vb    = graph * bpg + local;

    int v  = vb * NPB + threadIdx.x / D4;
    int f4 = threadIdx.x % D4;
    if (v >= n) return;
    const float4* h4 = reinterpret_cast<const float4*>(hs);
    int st = offs[v];
    int c  = cnt[v];
    float4 acc = h4[(size_t)v * D4 + f4];        // self term
    int j = 0;
    for (; j + 4 <= c; j += 4) {
        int s0 = csr_src[st + j],     s1 = csr_src[st + j + 1];
        int s2 = csr_src[st + j + 2], s3 = csr_src[st + j + 3];
        float4 h0 = h4[(size_t)s0 * D4 + f4];
        float4 h1 = h4[(size_t)s1 * D4 + f4];
        float4 h2 = h4[(size_t)s2 * D4 + f4];
        float4 h3 = h4[(size_t)s3 * D4 + f4];
        acc.x += h0.x + h1.x + h2.x + h3.x;
        acc.y += h0.y + h1.y + h2.y + h3.y;
        acc.z += h0.z + h1.z + h2.z + h3.z;
        acc.w += h0.w + h1.w + h2.w + h3.w;
    }
    for (; j < c; j++) {
        int s0 = csr_src[st + j];
        float4 h0 = h4[(size_t)s0 * D4 + f4];
        acc.x += h0.x; acc.y += h0.y; acc.z += h0.z; acc.w += h0.w;
    }
    float dv = dinv[v];
    float4 bb = reinterpret_cast<const float4*>(b)[f4];
    float4 o;
    o.x = acc.x * dv + bb.x;
    o.y = acc.y * dv + bb.y;
    o.z = acc.z * dv + bb.z;
    o.w = acc.w * dv + bb.w;
    reinterpret_cast<float4*>(out)[(size_t)v * D4 + f4] = o;
}

// ---------------------------------------------------------------- graphnorm partial sums (slot writes, no atomics)
template <int D4>   // 32 or 64
__global__ __launch_bounds__(256) void gn_partial_kernel(
        const float* __restrict__ x, float* __restrict__ sum1, float* __restrict__ sum2,
        int n_per) {
    constexpr int GROUPS = 256 / D4;
    __shared__ float4 l1[256];
    __shared__ float4 l2[256];
    int g = blockIdx.x >> 3;          // graph
    int ch = blockIdx.x & 7;          // node chunk (8 chunks)
    int f4 = threadIdx.x % D4;
    int grp = threadIdx.x / D4;
    int chunk = n_per / 8;
    int base = g * n_per + ch * chunk;
    const float4* x4 = reinterpret_cast<const float4*>(x);
    float4 s1 = {0.f, 0.f, 0.f, 0.f}, s2 = {0.f, 0.f, 0.f, 0.f};
    for (int i = grp; i < chunk; i += GROUPS) {
        float4 v = x4[(size_t)(base + i) * D4 + f4];
        s1.x += v.x; s1.y += v.y; s1.z += v.z; s1.w += v.w;
        s2.x += v.x * v.x; s2.y += v.y * v.y; s2.z += v.z * v.z; s2.w += v.w * v.w;
    }
    int t = threadIdx.x;
    l1[t] = s1; l2[t] = s2;
    __syncthreads();
    for (int str = 128; str >= D4; str >>= 1) {
        if (t < str) {
            float4 a = l1[t + str], b2 = l2[t + str];
            l1[t].x += a.x; l1[t].y += a.y; l1[t].z += a.z; l1[t].w += a.w;
            l2[t].x += b2.x; l2[t].y += b2.y; l2[t].z += b2.z; l2[t].w += b2.w;
        }
        __syncthreads();
    }
    if (t < D4) {
        size_t slot = (size_t)(g * 8 + ch) * (D4 * 4) + t * 4;
        *reinterpret_cast<float4*>(&sum1[slot]) = l1[t];
        *reinterpret_cast<float4*>(&sum2[slot]) = l2[t];
    }
}

__global__ void gn_final_kernel(const float* __restrict__ sum1, const float* __restrict__ sum2,
                                const float* __restrict__ ms, const float* __restrict__ w,
                                float* __restrict__ cmean, float* __restrict__ srw,
                                int n_per, int D, int total) {
    int t = blockIdx.x * blockDim.x + threadIdx.x;
    if (t >= total) return;
    int g = t / D;
    int f = t % D;
    float s1 = 0.f, s2 = 0.f;
    for (int ch = 0; ch < 8; ch++) {
        size_t slot = (size_t)(g * 8 + ch) * D + f;
        s1 += sum1[slot];
        s2 += sum2[slot];
    }
    float inv_n = 1.0f / (float)n_per;
    float mean = s1 * inv_n;
    float ex2  = s2 * inv_n;
    float m = ms[f];
    float var = ex2 - 2.f * m * mean * mean + m * m * mean * mean;
    cmean[t] = m * mean;
    srw[t]   = w[f] * rsqrtf(var + GN_EPS);
}

// ---------------------------------------------------------------- 1/||p|| for all 3 layers in one launch
__global__ void pnorm3_kernel(const float* __restrict__ p0, const float* __restrict__ p1,
                              const float* __restrict__ p2, int d0, int d1, int d2,
                              float* __restrict__ out) {
    __shared__ float red[256];
    const float* p = (blockIdx.x == 0) ? p0 : (blockIdx.x == 1) ? p1 : p2;
    int d          = (blockIdx.x == 0) ? d0 : (blockIdx.x == 1) ? d1 : d2;
    int t = threadIdx.x;
    float v = (t < d) ? p[t] : 0.0f;
    red[t] = v * v;
    __syncthreads();
    for (int s = 128; s; s >>= 1) {
        if (t < s) red[t] += red[t + s];
        __syncthreads();
    }
    if (t == 0) out[blockIdx.x] = 1.0f / sqrtf(red[0]);
}

// ---------------------------------------------------------------- graphnorm apply + relu + score
template <int DO>
__global__ __launch_bounds__(256) void gn_apply_score_kernel(
        float* __restrict__ x, const float* __restrict__ cmean, const float* __restrict__ srw,
        const float* __restrict__ bias, const float* __restrict__ p,
        const float* __restrict__ pinv, float* __restrict__ score, int n_per) {
    constexpr int V = DO / 64;
    int node = blockIdx.x * 4 + (threadIdx.x >> 6);
    int lane = threadIdx.x & 63;
    int g = node / n_per;
    float*       xr = x + (size_t)node * DO + lane * V;
    const float* cm = cmean + g * DO + lane * V;
    const float* sw = srw + g * DO + lane * V;
    const float* bb = bias + lane * V;
    const float* pp = p + lane * V;
    float dot = 0.f;
#pragma unroll
    for (int i = 0; i < V; i++) {
        float y = (xr[i] - cm[i]) * sw[i] + bb[i];
        y = fmaxf(y, 0.0f);
        xr[i] = y;
        dot += y * pp[i];
    }
#pragma unroll
    for (int off = 32; off; off >>= 1) dot += __shfl_xor(dot, off);
    if (lane == 0) score[node] = tanhf(dot * pinv[0]);
}

// ---------------------------------------------------------------- top-k via radix select
template <int N, int K>
__global__ __launch_bounds__(1024) void topk_radix_kernel(
        const float* __restrict__ score, int* __restrict__ mapping,
        int* __restrict__ inv) {
    __shared__ int hist[256];
    __shared__ int sscan[N];
    __shared__ int sbyte, sneed;
    const int g = blockIdx.x;
    const int t = threadIdx.x;       // blockDim == N
    float sc = score[g * N + t];
    unsigned u = __float_as_uint(sc);
    unsigned key = (u & 0x80000000u) ? ~u : (u | 0x80000000u);   // monotone

    unsigned prefix = 0;
    int need = K;
#pragma unroll
    for (int shift = 24; shift >= 0; shift -= 8) {
        if (t < 256) hist[t] = 0;
        __syncthreads();
        unsigned hm = (shift == 24) ? 0u : (0xFFFFFFFFu << (shift + 8));
        if ((key & hm) == (prefix & hm))
            atomicAdd(&hist[(key >> shift) & 255], 1);
        __syncthreads();
        if (t < 256) sscan[t] = hist[t];
        __syncthreads();
        for (int d = 1; d < 256; d <<= 1) {
            int x = (t < 256 && t + d < 256) ? sscan[t + d] : 0;
            __syncthreads();
            if (t < 256) sscan[t] += x;
            __syncthreads();
        }
        if (t < 256) {
            int ge  = sscan[t];
            int gt_ = (t + 1 < 256) ? sscan[t + 1] : 0;
            if (ge >= need && gt_ < need) { sbyte = t; sneed = need - gt_; }
        }
        __syncthreads();
        prefix |= ((unsigned)sbyte << shift);
        need = sneed;
        __syncthreads();
    }
    bool gt = key > prefix;
    bool eq = (key == prefix);
    sscan[t] = (gt ? (1 << 16) : 0) | (eq ? 1 : 0);
    __syncthreads();
    for (int d = 1; d < N; d <<= 1) {
        int x = (t >= d) ? sscan[t - d] : 0;
        __syncthreads();
        sscan[t] += x;
        __syncthreads();
    }
    int incl   = sscan[t];
    int gtrank = (incl >> 16) - (gt ? 1 : 0);
    int eqrank = (incl & 0xFFFF) - (eq ? 1 : 0);
    int cntGT  = K - need;
    bool sel = gt || (eq && (eqrank < need));
    int old_g = g * N + t;
    if (sel) {
        int slot = gt ? gtrank : (cntGT + eqrank);
        mapping[old_g] = g * K + slot;
        inv[g * K + slot] = old_g;
    } else {
        mapping[old_g] = -1;
    }
}

// ---------------------------------------------------------------- permute + scale by score
__global__ void permute_scale_kernel(const float* __restrict__ x, const int* __restrict__ inv,
                                     const float* __restrict__ score, float* __restrict__ xn,
                                     int total, int ldof4) {
    int t = blockIdx.x * blockDim.x + threadIdx.x;
    if (t >= total) return;
    int node = t >> ldof4;
    int f4   = t & ((1 << ldof4) - 1);
    int dof4 = 1 << ldof4;
    int old = inv[node];
    float sc = score[old];
    float4 v = reinterpret_cast<const float4*>(x)[(size_t)old * dof4 + f4];
    float4 o = {v.x * sc, v.y * sc, v.z * sc, v.w * sc};
    reinterpret_cast<float4*>(xn)[t] = o;
}

// ---------------------------------------------------------------- final mean/max pool (1024 thr, 4-chunk)
__global__ __launch_bounds__(1024) void pool_kernel(const float* __restrict__ x,
                                                    float* __restrict__ out, int n_per) {
    __shared__ float ssum[1024];
    __shared__ float smax[1024];
    int g = blockIdx.x;
    int f = threadIdx.x & 255;
    int ch = threadIdx.x >> 8;       // 0..3
    const float* xg = x + (size_t)g * n_per * 256;
    float s = 0.f, mx = -INFINITY;
    for (int i = ch; i < n_per; i += 4) {
        float v = xg[(size_t)i * 256 + f];
        s += v;
        mx = fmaxf(mx, v);
    }
    ssum[threadIdx.x] = s;
    smax[threadIdx.x] = mx;
    __syncthreads();
    if (ch == 0) {
#pragma unroll
        for (int c = 1; c < 4; c++) {
            s  += ssum[f + c * 256];
            mx  = fmaxf(mx, smax[f + c * 256]);
        }
        out[g * 512 + f]       = s / (float)n_per;
        out[g * 512 + 256 + f] = mx;
    }
}

// ================================================================ host
static inline int cdiv_h(int a, int b) { return (a + b - 1) / b; }

extern "C" void kernel_launch(void* const* d_in, const int* in_sizes, int n_in,
                              void* d_out, int out_size, void* d_ws, size_t ws_size,
                              hipStream_t stream) {
    (void)in_sizes; (void)n_in; (void)out_size; (void)ws_size;

    const float* x_in = (const float*)d_in[0];
    const int*   ei   = (const int*)d_in[1];
    // d_in[2] = batch (unused, equal-sized graphs)
    const float* Wm[3]  = {(const float*)d_in[3],  (const float*)d_in[9],  (const float*)d_in[15]};
    const float* bv[3]  = {(const float*)d_in[4],  (const float*)d_in[10], (const float*)d_in[16]};
    const float* gnw[3] = {(const float*)d_in[5],  (const float*)d_in[11], (const float*)d_in[17]};
    const float* gnb[3] = {(const float*)d_in[6],  (const float*)d_in[12], (const float*)d_in[18]};
    const float* gnm[3] = {(const float*)d_in[7],  (const float*)d_in[13], (const float*)d_in[19]};
    const float* pv[3]  = {(const float*)d_in[8],  (const float*)d_in[14], (const float*)d_in[20]};

    // workspace carve
    size_t off = 0;
    auto alloc = [&](size_t bytes) {
        void* p = (char*)d_ws + off;
        off += (bytes + 255) & ~(size_t)255;
        return p;
    };
    float* X1      = (float*)alloc((size_t)65536 * 128 * 4);   // gemm out
    float* H       = (float*)alloc((size_t)65536 * 128 * 4);   // Hs (row-scaled)
    float* X2      = (float*)alloc((size_t)32768 * 128 * 4);
    int*   csr_src = (int*)alloc((size_t)ETOT * 4);
    int*   cmap    = (int*)alloc(NTOT * 4);
    int*   cnt     = (int*)alloc(65536 * 4);
    int*   offs    = (int*)alloc(65536 * 4);
    float* dinv    = (float*)alloc(65536 * 4);
    float* score   = (float*)alloc(65536 * 4);
    int*   mapping = (int*)alloc(65536 * 4);
    int*   inv     = (int*)alloc(32768 * 4);
    float* sum1    = (float*)alloc(64 * 8 * 256 * 4);   // per-chunk slots
    float* sum2    = (float*)alloc(64 * 8 * 256 * 4);
    float* cmean   = (float*)alloc(64 * 256 * 4);
    float* srw     = (float*)alloc(64 * 256 * 4);
    float* pinv    = (float*)alloc(256);

    const int nper[4] = {1024, 512, 256, 128};
    const int din[3]  = {100, 128, 128};
    const int dof[3]  = {128, 128, 256};

    cmap_init_kernel<<<NTOT / 256, 256, 0, stream>>>(cmap);
    pnorm3_kernel<<<3, 256, 0, stream>>>(pv[0], pv[1], pv[2], dof[0], dof[1], dof[2], pinv);

    for (int L = 0; L < 3; L++) {
        const int n    = NB * nper[L];
        const int k    = nper[L + 1];
        const int nn   = NB * k;
        const int D    = dof[L];
        const int dof4 = D / 4;
        const int ldof4 = (dof4 == 32) ? 5 : 6;
        const float* xin = (L == 0) ? x_in : X2;

        // ---- fused CSR build from original edges + cmap
        if (nper[L] == 1024)
            csr_build_kernel<1024><<<NB, 1024, 0, stream>>>(ei, cmap, cnt, offs, dinv, csr_src);
        else if (nper[L] == 512)
            csr_build_kernel<512><<<NB, 1024, 0, stream>>>(ei, cmap, cnt, offs, dinv, csr_src);
        else
            csr_build_kernel<256><<<NB, 1024, 0, stream>>>(ei, cmap, cnt, offs, dinv, csr_src);

        // ---- Hs = (x @ W) * dinv[row]
        gemm128_kernel<<<dim3(n / 128, D / 128), 256, 0, stream>>>(xin, Wm[L], dinv, H,
                                                                   n, D, din[L]);

        // ---- fused aggregate: X1 = dinv*(Hs[v] + sum Hs[src]) + b
        if (dof4 == 32) {
            const int NPB = 8;
            const int bpg = nper[L] / NPB;
            gather_kernel<32><<<n / NPB, 256, 0, stream>>>(H, cnt, offs, dinv, csr_src,
                                                           bv[L], X1, n, bpg);
        } else {
            const int NPB = 4;
            const int bpg = nper[L] / NPB;
            gather_kernel<64><<<n / NPB, 256, 0, stream>>>(H, cnt, offs, dinv, csr_src,
                                                           bv[L], X1, n, bpg);
        }

        // ---- graphnorm stats
        if (dof4 == 32)
            gn_partial_kernel<32><<<NB * 8, 256, 0, stream>>>(X1, sum1, sum2, nper[L]);
        else
            gn_partial_kernel<64><<<NB * 8, 256, 0, stream>>>(X1, sum1, sum2, nper[L]);
        gn_final_kernel<<<cdiv_h(NB * D, 256), 256, 0, stream>>>(sum1, sum2, gnm[L], gnw[L],
                                                                 cmean, srw, nper[L], D, NB * D);
        if (D == 128)
            gn_apply_score_kernel<128><<<n / 4, 256, 0, stream>>>(X1, cmean, srw, gnb[L],
                                                                  pv[L], pinv + L, score, nper[L]);
        else
            gn_apply_score_kernel<256><<<n / 4, 256, 0, stream>>>(X1, cmean, srw, gnb[L],
                                                                  pv[L], pinv + L, score, nper[L]);

        // ---- top-k pooling (radix select)
        if (nper[L] == 1024)
            topk_radix_kernel<1024, 512><<<NB, 1024, 0, stream>>>(score, mapping, inv);
        else if (nper[L] == 512)
            topk_radix_kernel<512, 256><<<NB, 512, 0, stream>>>(score, mapping, inv);
        else
            topk_radix_kernel<256, 128><<<NB, 256, 0, stream>>>(score, mapping, inv);

        permute_scale_kernel<<<cdiv_h(nn * dof4, 256), 256, 0, stream>>>(X1, inv, score, X2,
                                                                         nn * dof4, ldof4);
        if (L < 2)
            compose_map_kernel<<<NTOT / 256, 256, 0, stream>>>(cmap, mapping);
    }

    // final mean/max pool -> [64, 512]
    pool_kernel<<<NB, 1024, 0, stream>>>(X2, (float*)d_out, nper[3]);
}